// Round 4
// baseline (277.836 us; speedup 1.0000x reference)
//
#include <hip/hip_runtime.h>
#include <hip/hip_bf16.h>

#define B_ 2
#define C_ 20000
#define H_ 64
#define M_ 8
#define E_ 200000
#define P_ 3
#define EPS_ 1e-12f
#define ET_ (E_ / 64)   // edge tiles per batch = 3125

typedef __attribute__((ext_vector_type(8))) short short8;
typedef __attribute__((ext_vector_type(4))) float float4v;

__device__ __forceinline__ float silu_(float x) {
    return x / (1.f + __expf(-x));
}
__device__ __forceinline__ unsigned short f2b(float f) {
    unsigned u = __float_as_uint(f);
    unsigned r = (u + 0x7FFF + ((u >> 16) & 1)) >> 16;   // RNE fp32->bf16
    return (unsigned short)r;
}
__device__ __forceinline__ float b2f(unsigned short h) {
    return __uint_as_float(((unsigned)h) << 16);
}
__device__ __forceinline__ unsigned pk2u(float a, float b) {
    __hip_bfloat162 h = __float22bfloat162_rn(make_float2(a, b)); // v_cvt_pk_bf16_f32
    unsigned u; __builtin_memcpy(&u, &h, sizeof(u)); return u;
}

// bf16 B-fragment-swizzled weights (K multiples of 32; W1 rows 128..131 on VALU)
#define W1S_OFF 0
#define W2S_OFF 8192
#define P1S_OFF 12288
#define U1S_OFF 16384
#define U2S_OFF 24576
#define WBUF_ELEMS 28672

__global__ __launch_bounds__(256) void prep_kernel(
    const float* __restrict__ W1, const float* __restrict__ W2,
    const float* __restrict__ P1, const float* __restrict__ U1,
    const float* __restrict__ U2, unsigned short* __restrict__ wbuf)
{
    int t = blockIdx.x * 256 + threadIdx.x;
    if (t >= WBUF_ELEMS) return;
    const float* W; int e;
    if (t < W2S_OFF)      { W = W1; e = t; }
    else if (t < U1S_OFF) { W = (t < P1S_OFF) ? W2 : P1; e = (t < P1S_OFF) ? t - W2S_OFF : t - P1S_OFF; }
    else if (t < U2S_OFF) { W = U1; e = t - U1S_OFF; }
    else                  { W = U2; e = t - U2S_OFF; }
    int j = e & 7, lane = (e >> 3) & 63, nt = (e >> 9) & 3, kk = e >> 11;
    int k = kk * 32 + ((lane >> 4) * 8) + j;
    int n = nt * 16 + (lane & 15);
    wbuf[t] = f2b(W[k * 64 + n]);
}

// ---------------------------------------------------------------------------
// CSR build: hist -> scan (1 block, wave-scan) -> scatter (dst-sorted edges)
// ---------------------------------------------------------------------------
__global__ __launch_bounds__(256) void hist_kernel(
    const int* __restrict__ ei, int* __restrict__ cnt)
{
    int e = blockIdx.x * 256 + threadIdx.x;
    if (e >= E_) return;
    atomicAdd(&cnt[ei[E_ + e]], 1);
}

__global__ __launch_bounds__(1024) void scan_kernel(
    const int* __restrict__ cnt, int* __restrict__ off, int* __restrict__ cursor)
{
    __shared__ int wsum[16];
    __shared__ int carry_s;
    const int t = threadIdx.x, w = t >> 6, l = t & 63;
    if (t == 0) carry_s = 0;
    __syncthreads();
    for (int base = 0; base < C_; base += 1024) {
        int idx = base + t;
        int v = (idx < C_) ? cnt[idx] : 0;
        int inc = v;
        #pragma unroll
        for (int s = 1; s < 64; s <<= 1) {
            int n = __shfl_up(inc, s);
            if (l >= s) inc += n;
        }
        if (l == 63) wsum[w] = inc;
        __syncthreads();
        if (w == 0 && l < 16) {
            int x = wsum[l];
            int inc2 = x;
            #pragma unroll
            for (int s = 1; s < 16; s <<= 1) {
                int n = __shfl_up(inc2, s);
                if (l >= s) inc2 += n;
            }
            wsum[l] = inc2 - x;   // exclusive wave offsets
        }
        __syncthreads();
        int ex = inc - v + wsum[w] + carry_s;
        if (idx < C_) { off[idx] = ex; cursor[idx] = ex; }
        __syncthreads();
        if (t == 1023) carry_s = ex + v;   // carry + chunk total
        __syncthreads();
    }
    if (t == 0) off[C_] = E_;
}

__global__ __launch_bounds__(256) void scatter_kernel(
    const int* __restrict__ ei, int* __restrict__ cursor,
    int* __restrict__ ssrc, int* __restrict__ sdst)
{
    int e = blockIdx.x * 256 + threadIdx.x;
    if (e >= E_) return;
    int s = ei[e], d = ei[E_ + e];
    int slot = atomicAdd(&cursor[d], 1);
    ssrc[slot] = s;
    sdst[slot] = d;
}

// ---------------------------------------------------------------------------
// Per-(b,cell) descriptor: 8 x (x,y,z,mask) + (centroid_x,y,z, msum). 40 floats.
// ---------------------------------------------------------------------------
__global__ __launch_bounds__(256) void desc_kernel(
    const float* __restrict__ pos, const int* __restrict__ cni,
    const float* __restrict__ mask, float* __restrict__ desc)
{
    int tid = blockIdx.x * 256 + threadIdx.x;
    if (tid >= B_ * C_) return;
    int b = tid / C_, c = tid - b * C_;
    const float* pb = pos + (size_t)b * C_ * P_;
    float4* D = (float4*)(desc + (size_t)tid * 40);
    int4 n0 = *(const int4*)&cni[c*8];
    int4 n1 = *(const int4*)&cni[c*8 + 4];
    float4 m0 = *(const float4*)&mask[c*8];
    float4 m1 = *(const float4*)&mask[c*8 + 4];
    int ni[8] = {n0.x, n0.y, n0.z, n0.w, n1.x, n1.y, n1.z, n1.w};
    float mm[8] = {m0.x, m0.y, m0.z, m0.w, m1.x, m1.y, m1.z, m1.w};
    float sx = 0.f, sy = 0.f, sz = 0.f, sm = 0.f;
    #pragma unroll
    for (int m = 0; m < 8; ++m) {
        float x = pb[ni[m]*3+0], y = pb[ni[m]*3+1], z = pb[ni[m]*3+2];
        D[m] = make_float4(x, y, z, mm[m]);
        sx += x * mm[m]; sy += y * mm[m]; sz += z * mm[m]; sm += mm[m];
    }
    float inv = 1.f / fmaxf(sm, EPS_);
    D[8] = make_float4(sx * inv, sy * inv, sz * inv, sm);
}

// ---------------------------------------------------------------------------
// Geometry in dst-sorted domain: coalesced index/inv4 IO, descriptor reads.
// ---------------------------------------------------------------------------
__global__ __launch_bounds__(256) void geom_kernel(
    const float* __restrict__ pos, const int* __restrict__ ssrc,
    const int* __restrict__ sdst, const float* __restrict__ desc,
    float* __restrict__ inv4)
{
    int tid = blockIdx.x * 256 + threadIdx.x;
    if (tid >= B_ * E_) return;
    int b = tid / E_, i = tid - b * E_;
    int s = ssrc[i], d = sdst[i];
    const float* pb = pos + (size_t)b * C_ * P_;

    float rx = pb[s*3+0] - pb[d*3+0];
    float ry = pb[s*3+1] - pb[d*3+1];
    float rz = pb[s*3+2] - pb[d*3+2];
    float dist = sqrtf(rx*rx + ry*ry + rz*rz);

    const float4* Ds = (const float4*)(desc + ((size_t)b * C_ + s) * 40);
    const float4* Dd = (const float4*)(desc + ((size_t)b * C_ + d) * 40);
    float4 S[9], D[9];
    #pragma unroll
    for (int m = 0; m < 9; ++m) { S[m] = Ds[m]; D[m] = Dd[m]; }
    float sp2[8], dp2[8];
    #pragma unroll
    for (int m = 0; m < 8; ++m) {
        sp2[m] = S[m].x*S[m].x + S[m].y*S[m].y + S[m].z*S[m].z;
        dp2[m] = D[m].x*D[m].x + D[m].y*D[m].y + D[m].z*D[m].z;
    }
    const float INFV = __builtin_inff();
    float pair = 0.f, hxy = 0.f;
    float colmin[8];
    #pragma unroll
    for (int j = 0; j < 8; ++j) colmin[j] = INFV;
    #pragma unroll
    for (int ii = 0; ii < 8; ++ii) {
        float rowmin = INFV;
        #pragma unroll
        for (int j = 0; j < 8; ++j) {
            float cr = S[ii].x*D[j].x + S[ii].y*D[j].y + S[ii].z*D[j].z;
            float dd = sqrtf(fmaxf(sp2[ii] + dp2[j] - 2.f*cr, 0.f) + EPS_);
            pair += dd * S[ii].w * D[j].w;
            rowmin    = (D[j].w  > 0.f) ? fminf(rowmin, dd)    : rowmin;
            colmin[j] = (S[ii].w > 0.f) ? fminf(colmin[j], dd) : colmin[j];
        }
        hxy = fmaxf(hxy, (S[ii].w > 0.f) ? rowmin : 0.f);
    }
    float hyx = 0.f;
    #pragma unroll
    for (int j = 0; j < 8; ++j)
        hyx = fmaxf(hyx, (D[j].w > 0.f) ? colmin[j] : 0.f);
    float haus = fmaxf(hxy, hyx);

    float ddx = S[8].x - D[8].x, ddy = S[8].y - D[8].y, ddz = S[8].z - D[8].z;
    float centroid = sqrtf(ddx*ddx + ddy*ddy + ddz*ddz);

    ((float4*)inv4)[tid] = make_float4(dist, pair, centroid, haus);
}

// ---------------------------------------------------------------------------
// Edge MLPs via MFMA, dst-sorted domain, barrier-free wave-private strips.
// Messages -> contiguous bf16 streaming stores (no agg atomics).
// ---------------------------------------------------------------------------
__global__ __launch_bounds__(256) void edge_kernel(
    const float* __restrict__ feat, const float* __restrict__ pos,
    const int* __restrict__ ssrc, const int* __restrict__ sdst,
    const float* __restrict__ inv4,
    const unsigned short* __restrict__ wbuf, const float* __restrict__ W1,
    const float* __restrict__ b1, const float* __restrict__ b2,
    const float* __restrict__ pb1, const float* __restrict__ P2,
    const float* __restrict__ pb2,
    unsigned short* __restrict__ Msort, float* __restrict__ out_pos)
{
    __shared__ unsigned short lds[4 * 3328];   // 26624 B

    const int tid  = threadIdx.x;
    const int w    = tid >> 6;
    const int lane = tid & 63;
    const int q    = lane >> 4;
    const int l16  = lane & 15;

    const int tile = blockIdx.x;
    const int b    = tile / ET_;
    const int i0   = (tile - b * ET_) * 64;
    const int s_l  = ssrc[i0 + lane];
    const int d_l  = sdst[i0 + lane];
    const float* fb = feat + (size_t)b * C_ * H_;

    unsigned short* Xw = lds + w * 3328;
    unsigned short* Hw = Xw + 2176;
    unsigned short* Mw = Xw;   // alias: X dead before M written (dep chain)

    const int rr4 = lane >> 4, c4 = lane & 15;
    #pragma unroll
    for (int it = 0; it < 4; ++it) {
        int rloc = it * 4 + rr4;
        int r = w * 16 + rloc;
        int sr = __shfl(s_l, r);
        int dr = __shfl(d_l, r);
        float4 vs = *(const float4*)&fb[(size_t)sr * 64 + c4 * 4];
        float4 vd = *(const float4*)&fb[(size_t)dr * 64 + c4 * 4];
        *(uint2*)&Xw[rloc*136 + c4*4]      = make_uint2(pk2u(vs.x, vs.y), pk2u(vs.z, vs.w));
        *(uint2*)&Xw[rloc*136 + 64 + c4*4] = make_uint2(pk2u(vd.x, vd.y), pk2u(vd.z, vd.w));
    }

    // layer 1: MFMA over k<128 + fp32 invariant tail
    float4v acc[4];
    #pragma unroll
    for (int nt = 0; nt < 4; ++nt) {
        float bv = b1[nt*16 + l16];
        acc[nt] = (float4v){bv, bv, bv, bv};
    }
    #pragma unroll
    for (int kk = 0; kk < 4; ++kk) {
        short8 a = *(const short8*)&Xw[l16*136 + kk*32 + q*8];
        #pragma unroll
        for (int nt = 0; nt < 4; ++nt) {
            short8 bf = *(const short8*)&wbuf[W1S_OFF + (((kk*4 + nt)*64) + lane) * 8];
            acc[nt] = __builtin_amdgcn_mfma_f32_16x16x32_bf16(a, bf, acc[nt], 0, 0, 0);
        }
    }
    float4 iv[4];
    #pragma unroll
    for (int i = 0; i < 4; ++i)
        iv[i] = ((const float4*)inv4)[(size_t)b * E_ + i0 + w*16 + q*4 + i];
    #pragma unroll
    for (int nt = 0; nt < 4; ++nt) {
        float wa = W1[128*64 + nt*16 + l16];
        float wb = W1[129*64 + nt*16 + l16];
        float wc = W1[130*64 + nt*16 + l16];
        float wd = W1[131*64 + nt*16 + l16];
        #pragma unroll
        for (int i = 0; i < 4; ++i)
            acc[nt][i] += iv[i].x*wa + iv[i].y*wb + iv[i].z*wc + iv[i].w*wd;
    }
    #pragma unroll
    for (int nt = 0; nt < 4; ++nt)
        #pragma unroll
        for (int i = 0; i < 4; ++i)
            Hw[(q*4 + i)*72 + nt*16 + l16] = f2b(silu_(acc[nt][i]));

    // layer 2 -> messages
    float4v mac[4];
    #pragma unroll
    for (int nt = 0; nt < 4; ++nt) {
        float bv = b2[nt*16 + l16];
        mac[nt] = (float4v){bv, bv, bv, bv};
    }
    #pragma unroll
    for (int kk = 0; kk < 2; ++kk) {
        short8 a = *(const short8*)&Hw[l16*72 + kk*32 + q*8];
        #pragma unroll
        for (int nt = 0; nt < 4; ++nt) {
            short8 bf = *(const short8*)&wbuf[W2S_OFF + (((kk*4 + nt)*64) + lane) * 8];
            mac[nt] = __builtin_amdgcn_mfma_f32_16x16x32_bf16(a, bf, mac[nt], 0, 0, 0);
        }
    }
    #pragma unroll
    for (int nt = 0; nt < 4; ++nt)
        #pragma unroll
        for (int i = 0; i < 4; ++i)
            Mw[(q*4 + i)*72 + nt*16 + l16] = f2b(mac[nt][i]);

    // gate: wt = tanh(silu(M @ P1 + pb1) @ P2 + pb2)
    float4v gac[4];
    #pragma unroll
    for (int nt = 0; nt < 4; ++nt) {
        float bv = pb1[nt*16 + l16];
        gac[nt] = (float4v){bv, bv, bv, bv};
    }
    #pragma unroll
    for (int kk = 0; kk < 2; ++kk) {
        short8 a = *(const short8*)&Mw[l16*72 + kk*32 + q*8];
        #pragma unroll
        for (int nt = 0; nt < 4; ++nt) {
            short8 bf = *(const short8*)&wbuf[P1S_OFF + (((kk*4 + nt)*64) + lane) * 8];
            gac[nt] = __builtin_amdgcn_mfma_f32_16x16x32_bf16(a, bf, gac[nt], 0, 0, 0);
        }
    }
    float p2v[4];
    #pragma unroll
    for (int nt = 0; nt < 4; ++nt) p2v[nt] = P2[nt*16 + l16];
    const float pb2v = pb2[0];

    float* opb = out_pos + (size_t)b * C_ * P_;
    const float* pp = pos + (size_t)b * C_ * P_;

    #pragma unroll
    for (int i = 0; i < 4; ++i) {
        float p = 0.f;
        #pragma unroll
        for (int nt = 0; nt < 4; ++nt) p += silu_(gac[nt][i]) * p2v[nt];
        p += __shfl_xor(p, 8);
        p += __shfl_xor(p, 4);
        p += __shfl_xor(p, 2);
        p += __shfl_xor(p, 1);
        float wt = tanhf(p + pb2v);
        int r  = w*16 + q*4 + i;
        int sr = __shfl(s_l, r);
        int dr = __shfl(d_l, r);
        if (l16 < 3) {
            float rel = pp[sr*3 + l16] - pp[dr*3 + l16];
            atomicAdd(&opb[dr*3 + l16], wt * rel);
        }
    }

    // messages -> contiguous bf16 rows (fully coalesced, 512 B per store inst)
    unsigned short* Mg = Msort + ((size_t)b * E_ + i0 + w*16) * 64;
    #pragma unroll
    for (int it = 0; it < 4; ++it) {
        int row = it * 4 + rr4;
        uint2 v = *(const uint2*)&Mw[row*72 + c4*4];
        *(uint2*)&Mg[row*64 + c4*4] = v;
    }
}

// ---------------------------------------------------------------------------
// Segment-sum of contiguous message rows per dst node; apply 1/max(deg,1);
// write bf16 agg rows.
// ---------------------------------------------------------------------------
__global__ __launch_bounds__(256) void agg_kernel(
    const unsigned short* __restrict__ Msort, const int* __restrict__ off,
    const float* __restrict__ deg, unsigned short* __restrict__ aggb)
{
    int wid = (blockIdx.x * 256 + threadIdx.x) >> 6;
    int lane = threadIdx.x & 63;
    if (wid >= B_ * C_) return;
    int b = wid / C_, c = wid - b * C_;
    int j0 = off[c], j1 = off[c + 1];
    const unsigned short* Mb = Msort + (size_t)b * E_ * 64;
    float acc = 0.f;
    for (int j = j0; j < j1; ++j)
        acc += b2f(Mb[(size_t)j * 64 + lane]);
    float sc = 1.f / fmaxf(deg[c], 1.f);
    aggb[(size_t)wid * 64 + lane] = f2b(acc * sc);
}

// ---------------------------------------------------------------------------
// Node update via MFMA, barrier-free wave-private strips.
// ---------------------------------------------------------------------------
__global__ __launch_bounds__(256) void node_kernel(
    const float* __restrict__ feat, const unsigned short* __restrict__ aggb,
    const unsigned short* __restrict__ wbuf,
    const float* __restrict__ ub1, const float* __restrict__ ub2,
    float* __restrict__ out_feat)
{
    __shared__ unsigned short lds[4 * 3328];

    const int tid  = threadIdx.x;
    const int w    = tid >> 6;
    const int lane = tid & 63;
    const int q    = lane >> 4;
    const int l16  = lane & 15;
    const int g0   = blockIdx.x * 64;

    unsigned short* Xw = lds + w * 3328;
    unsigned short* Hw = Xw + 2176;

    const int rr4 = lane >> 4, c4 = lane & 15;
    #pragma unroll
    for (int it = 0; it < 4; ++it) {
        int rloc = it * 4 + rr4;
        int g = g0 + w*16 + rloc;
        float4 vf = *(const float4*)&feat[(size_t)g * 64 + c4 * 4];
        uint2  va = *(const uint2*)&aggb[(size_t)g * 64 + c4 * 4];
        *(uint2*)&Xw[rloc*136 + c4*4]      = make_uint2(pk2u(vf.x, vf.y), pk2u(vf.z, vf.w));
        *(uint2*)&Xw[rloc*136 + 64 + c4*4] = va;
    }

    float4v acc[4];
    #pragma unroll
    for (int nt = 0; nt < 4; ++nt) {
        float bv = ub1[nt*16 + l16];
        acc[nt] = (float4v){bv, bv, bv, bv};
    }
    #pragma unroll
    for (int kk = 0; kk < 4; ++kk) {
        short8 a = *(const short8*)&Xw[l16*136 + kk*32 + q*8];
        #pragma unroll
        for (int nt = 0; nt < 4; ++nt) {
            short8 bf = *(const short8*)&wbuf[U1S_OFF + (((kk*4 + nt)*64) + lane) * 8];
            acc[nt] = __builtin_amdgcn_mfma_f32_16x16x32_bf16(a, bf, acc[nt], 0, 0, 0);
        }
    }
    #pragma unroll
    for (int nt = 0; nt < 4; ++nt)
        #pragma unroll
        for (int i = 0; i < 4; ++i)
            Hw[(q*4 + i)*72 + nt*16 + l16] = f2b(silu_(acc[nt][i]));

    float4v oac[4];
    #pragma unroll
    for (int nt = 0; nt < 4; ++nt) {
        float bv = ub2[nt*16 + l16];
        oac[nt] = (float4v){bv, bv, bv, bv};
    }
    #pragma unroll
    for (int kk = 0; kk < 2; ++kk) {
        short8 a = *(const short8*)&Hw[l16*72 + kk*32 + q*8];
        #pragma unroll
        for (int nt = 0; nt < 4; ++nt) {
            short8 bf = *(const short8*)&wbuf[U2S_OFF + (((kk*4 + nt)*64) + lane) * 8];
            oac[nt] = __builtin_amdgcn_mfma_f32_16x16x32_bf16(a, bf, oac[nt], 0, 0, 0);
        }
    }
    #pragma unroll
    for (int nt = 0; nt < 4; ++nt)
        #pragma unroll
        for (int i = 0; i < 4; ++i) {
            size_t idx = (size_t)(g0 + w*16 + q*4 + i) * 64 + nt*16 + l16;
            out_feat[idx] = feat[idx] + oac[nt][i];
        }
}

extern "C" void kernel_launch(void* const* d_in, const int* in_sizes, int n_in,
                              void* d_out, int out_size, void* d_ws, size_t ws_size,
                              hipStream_t stream) {
    const float* feat = (const float*)d_in[0];
    const float* pos  = (const float*)d_in[1];
    const int*   ei   = (const int*)d_in[2];
    const float* deg  = (const float*)d_in[3];
    const int*   cni  = (const int*)d_in[4];
    const float* mask = (const float*)d_in[5];
    const float* W1   = (const float*)d_in[6];
    const float* b1   = (const float*)d_in[7];
    const float* W2   = (const float*)d_in[8];
    const float* b2   = (const float*)d_in[9];
    const float* P1   = (const float*)d_in[10];
    const float* pb1  = (const float*)d_in[11];
    const float* P2   = (const float*)d_in[12];
    const float* pb2  = (const float*)d_in[13];
    const float* U1   = (const float*)d_in[14];
    const float* ub1  = (const float*)d_in[15];
    const float* U2   = (const float*)d_in[16];
    const float* ub2  = (const float*)d_in[17];

    float* out_feat = (float*)d_out;                       // B*C*H
    float* out_pos  = out_feat + (size_t)B_ * C_ * H_;     // B*C*P

    // workspace layout (~71 MB)
    float* inv4 = (float*)d_ws;                                  // B*E*4 fp32
    float* desc = inv4 + (size_t)B_ * E_ * 4;                    // B*C*40 fp32
    unsigned short* wbuf  = (unsigned short*)(desc + (size_t)B_ * C_ * 40);
    unsigned short* Msort = wbuf + WBUF_ELEMS;                   // B*E*64 bf16
    unsigned short* aggb  = Msort + (size_t)B_ * E_ * 64;        // B*C*64 bf16
    int* cnt    = (int*)(aggb + (size_t)B_ * C_ * 64);           // C
    int* cursor = cnt + C_;                                      // C
    int* off    = cursor + C_;                                   // C+1
    int* ssrc   = off + C_ + 1;                                  // E
    int* sdst   = ssrc + E_;                                     // E

    hipMemsetAsync(cnt, 0, C_ * sizeof(int), stream);
    hipMemcpyAsync(out_pos, pos, (size_t)B_ * C_ * P_ * sizeof(float),
                   hipMemcpyDeviceToDevice, stream);

    prep_kernel<<<(WBUF_ELEMS + 255) / 256, 256, 0, stream>>>(W1, W2, P1, U1, U2, wbuf);
    hist_kernel<<<(E_ + 255) / 256, 256, 0, stream>>>(ei, cnt);
    desc_kernel<<<(B_ * C_ + 255) / 256, 256, 0, stream>>>(pos, cni, mask, desc);
    scan_kernel<<<1, 1024, 0, stream>>>(cnt, off, cursor);
    scatter_kernel<<<(E_ + 255) / 256, 256, 0, stream>>>(ei, cursor, ssrc, sdst);

    geom_kernel<<<(B_ * E_ + 255) / 256, 256, 0, stream>>>(pos, ssrc, sdst, desc, inv4);

    edge_kernel<<<B_ * ET_, 256, 0, stream>>>(
        feat, pos, ssrc, sdst, inv4, wbuf, W1, b1, b2, pb1, P2, pb2, Msort, out_pos);

    agg_kernel<<<(B_ * C_) / 4, 256, 0, stream>>>(Msort, off, deg, aggb);

    node_kernel<<<(B_ * C_) / 64, 256, 0, stream>>>(
        feat, aggb, wbuf, ub1, ub2, out_feat);
}

// Round 5
// 247.091 us; speedup vs baseline: 1.1244x; 1.1244x over previous
//
#include <hip/hip_runtime.h>
#include <hip/hip_bf16.h>

#define B_ 2
#define C_ 20000
#define H_ 64
#define M_ 8
#define E_ 200000
#define P_ 3
#define EPS_ 1e-12f
#define ET_ (E_ / 64)   // edge tiles per batch = 3125

typedef __attribute__((ext_vector_type(8))) short short8;
typedef __attribute__((ext_vector_type(4))) float float4v;

__device__ __forceinline__ float silu_(float x) {
    return x / (1.f + __expf(-x));
}
__device__ __forceinline__ unsigned short f2b(float f) {
    unsigned u = __float_as_uint(f);
    unsigned r = (u + 0x7FFF + ((u >> 16) & 1)) >> 16;   // RNE fp32->bf16
    return (unsigned short)r;
}
__device__ __forceinline__ float b2f(unsigned short h) {
    return __uint_as_float(((unsigned)h) << 16);
}
__device__ __forceinline__ unsigned pk2u(float a, float b) {
    __hip_bfloat162 h = __float22bfloat162_rn(make_float2(a, b)); // v_cvt_pk_bf16_f32
    unsigned u; __builtin_memcpy(&u, &h, sizeof(u)); return u;
}

// bf16 B-fragment-swizzled weights (K multiples of 32; W1 rows 128..131 on VALU)
#define W1S_OFF 0
#define W2S_OFF 8192
#define P1S_OFF 12288
#define U1S_OFF 16384
#define U2S_OFF 24576
#define WBUF_ELEMS 28672

__global__ __launch_bounds__(256) void prep_kernel(
    const float* __restrict__ W1, const float* __restrict__ W2,
    const float* __restrict__ P1, const float* __restrict__ U1,
    const float* __restrict__ U2, unsigned short* __restrict__ wbuf)
{
    int t = blockIdx.x * 256 + threadIdx.x;
    if (t >= WBUF_ELEMS) return;
    const float* W; int e;
    if (t < W2S_OFF)      { W = W1; e = t; }
    else if (t < U1S_OFF) { W = (t < P1S_OFF) ? W2 : P1; e = (t < P1S_OFF) ? t - W2S_OFF : t - P1S_OFF; }
    else if (t < U2S_OFF) { W = U1; e = t - U1S_OFF; }
    else                  { W = U2; e = t - U2S_OFF; }
    int j = e & 7, lane = (e >> 3) & 63, nt = (e >> 9) & 3, kk = e >> 11;
    int k = kk * 32 + ((lane >> 4) * 8) + j;
    int n = nt * 16 + (lane & 15);
    wbuf[t] = f2b(W[k * 64 + n]);
}

// ---------------------------------------------------------------------------
// CSR build (order-free): hist -> alloc (wave-scan + atomic bump) -> scatter
// ---------------------------------------------------------------------------
__global__ __launch_bounds__(256) void hist_kernel(
    const int* __restrict__ ei, int* __restrict__ cnt)
{
    int e = blockIdx.x * 256 + threadIdx.x;
    if (e >= E_) return;
    atomicAdd(&cnt[ei[E_ + e]], 1);
}

__global__ __launch_bounds__(256) void alloc_kernel(
    const int* __restrict__ cnt, int* __restrict__ off,
    int* __restrict__ cursor, int* __restrict__ total)
{
    int idx = blockIdx.x * 256 + threadIdx.x;
    int lane = threadIdx.x & 63;
    int v = (idx < C_) ? cnt[idx] : 0;
    int inc = v;
    #pragma unroll
    for (int s = 1; s < 64; s <<= 1) {
        int n = __shfl_up(inc, s);
        if (lane >= s) inc += n;
    }
    int wtot = __shfl(inc, 63);
    int base = 0;
    if (lane == 0) base = atomicAdd(total, wtot);
    base = __shfl(base, 0);
    if (idx < C_) {
        int o = base + inc - v;
        off[idx] = o;
        cursor[idx] = o;
    }
}

__global__ __launch_bounds__(256) void scatter_kernel(
    const int* __restrict__ ei, int* __restrict__ cursor,
    int* __restrict__ ssrc, int* __restrict__ sdst)
{
    int e = blockIdx.x * 256 + threadIdx.x;
    if (e >= E_) return;
    int s = ei[e], d = ei[E_ + e];
    int slot = atomicAdd(&cursor[d], 1);
    ssrc[slot] = s;
    sdst[slot] = d;
}

// ---------------------------------------------------------------------------
// Per-(b,cell) descriptor: 8 x (x,y,z,mask) + (centroid,msum) + (own pos).
// 40 floats (10 float4).
// ---------------------------------------------------------------------------
__global__ __launch_bounds__(256) void desc_kernel(
    const float* __restrict__ pos, const int* __restrict__ cni,
    const float* __restrict__ mask, float* __restrict__ desc)
{
    int tid = blockIdx.x * 256 + threadIdx.x;
    if (tid >= B_ * C_) return;
    int b = tid / C_, c = tid - b * C_;
    const float* pb = pos + (size_t)b * C_ * P_;
    float4* D = (float4*)(desc + (size_t)tid * 40);
    int4 n0 = *(const int4*)&cni[c*8];
    int4 n1 = *(const int4*)&cni[c*8 + 4];
    float4 m0 = *(const float4*)&mask[c*8];
    float4 m1 = *(const float4*)&mask[c*8 + 4];
    int ni[8] = {n0.x, n0.y, n0.z, n0.w, n1.x, n1.y, n1.z, n1.w};
    float mm[8] = {m0.x, m0.y, m0.z, m0.w, m1.x, m1.y, m1.z, m1.w};
    float sx = 0.f, sy = 0.f, sz = 0.f, sm = 0.f;
    #pragma unroll
    for (int m = 0; m < 8; ++m) {
        float x = pb[ni[m]*3+0], y = pb[ni[m]*3+1], z = pb[ni[m]*3+2];
        D[m] = make_float4(x, y, z, mm[m]);
        sx += x * mm[m]; sy += y * mm[m]; sz += z * mm[m]; sm += mm[m];
    }
    float inv = 1.f / fmaxf(sm, EPS_);
    D[8] = make_float4(sx * inv, sy * inv, sz * inv, sm);
    D[9] = make_float4(pb[c*3+0], pb[c*3+1], pb[c*3+2], 0.f);
}

// ---------------------------------------------------------------------------
// Edge kernel: fused geometry + 3 MFMA MLP stages. 4 independent waves/block,
// 16 edges per wave, barrier-free. Geometry split 4-way across quads (j-cols),
// combined with shfl_xor butterflies. Outputs: Msort rows + wt per edge.
// ---------------------------------------------------------------------------
__global__ __launch_bounds__(256) void edge_kernel(
    const float* __restrict__ feat,
    const int* __restrict__ ssrc, const int* __restrict__ sdst,
    const float* __restrict__ desc,
    const unsigned short* __restrict__ wbuf, const float* __restrict__ W1,
    const float* __restrict__ b1, const float* __restrict__ b2,
    const float* __restrict__ pb1, const float* __restrict__ P2,
    const float* __restrict__ pb2,
    unsigned short* __restrict__ Msort, float* __restrict__ wts)
{
    __shared__ unsigned short lds[4 * 3328];   // 26624 B

    const int tid  = threadIdx.x;
    const int w    = tid >> 6;
    const int lane = tid & 63;
    const int q    = lane >> 4;
    const int l16  = lane & 15;

    const int tile = blockIdx.x;
    const int b    = tile / ET_;
    const int i0   = (tile - b * ET_) * 64;
    const int s_l  = ssrc[i0 + lane];
    const int d_l  = sdst[i0 + lane];
    const float* fb = feat + (size_t)b * C_ * H_;

    unsigned short* Xw = lds + w * 3328;
    unsigned short* Hw = Xw + 2176;
    unsigned short* Mw = Xw;   // alias: X dead before M written (dep chain)

    // ================= geometry (edge = w*16 + l16, j-split across quads) ====
    const int sg = __shfl(s_l, w*16 + l16);
    const int dg = __shfl(d_l, w*16 + l16);
    const float4* Ds = (const float4*)(desc + ((size_t)b * C_ + sg) * 40);
    const float4* Dd = (const float4*)(desc + ((size_t)b * C_ + dg) * 40);

    float4 S[8];
    float sp2[8], rowmin[8];
    const float INFV = __builtin_inff();
    #pragma unroll
    for (int i = 0; i < 8; ++i) {
        S[i] = Ds[i];
        sp2[i] = S[i].x*S[i].x + S[i].y*S[i].y + S[i].z*S[i].z;
        rowmin[i] = INFV;
    }
    float pair = 0.f, hyx = 0.f;
    #pragma unroll
    for (int jj = 0; jj < 2; ++jj) {
        float4 Dj = Dd[q*2 + jj];
        float dp2 = Dj.x*Dj.x + Dj.y*Dj.y + Dj.z*Dj.z;
        float colmin = INFV;
        #pragma unroll
        for (int i = 0; i < 8; ++i) {
            float cr = S[i].x*Dj.x + S[i].y*Dj.y + S[i].z*Dj.z;
            float dd = sqrtf(fmaxf(sp2[i] + dp2 - 2.f*cr, 0.f) + EPS_);
            pair += dd * S[i].w * Dj.w;
            rowmin[i] = (Dj.w  > 0.f) ? fminf(rowmin[i], dd) : rowmin[i];
            colmin    = (S[i].w > 0.f) ? fminf(colmin, dd)    : colmin;
        }
        hyx = fmaxf(hyx, (Dj.w > 0.f) ? colmin : 0.f);
    }
    // combine the 4 quad-partials (lanes l16, l16+16, l16+32, l16+48)
    pair += __shfl_xor(pair, 16);  pair += __shfl_xor(pair, 32);
    hyx = fmaxf(hyx, __shfl_xor(hyx, 16));  hyx = fmaxf(hyx, __shfl_xor(hyx, 32));
    #pragma unroll
    for (int i = 0; i < 8; ++i) {
        rowmin[i] = fminf(rowmin[i], __shfl_xor(rowmin[i], 16));
        rowmin[i] = fminf(rowmin[i], __shfl_xor(rowmin[i], 32));
    }
    float hxy = 0.f;
    #pragma unroll
    for (int i = 0; i < 8; ++i)
        hxy = fmaxf(hxy, (S[i].w > 0.f) ? rowmin[i] : 0.f);
    float4 Sc = Ds[8], Dc = Dd[8];
    float cdx = Sc.x - Dc.x, cdy = Sc.y - Dc.y, cdz = Sc.z - Dc.z;
    float4 Sp = Ds[9], Dp = Dd[9];
    float pdx = Sp.x - Dp.x, pdy = Sp.y - Dp.y, pdz = Sp.z - Dp.z;
    const float ivx = sqrtf(pdx*pdx + pdy*pdy + pdz*pdz);       // dist
    const float ivy = pair;                                     // pairwise
    const float ivz = sqrtf(cdx*cdx + cdy*cdy + cdz*cdz);       // centroid
    const float ivw = fmaxf(hxy, hyx);                          // hausdorff

    // ================= stage X = [h_src | h_dst] bf16 ========================
    const int rr4 = lane >> 4, c4 = lane & 15;
    #pragma unroll
    for (int it = 0; it < 4; ++it) {
        int rloc = it * 4 + rr4;
        int r = w * 16 + rloc;
        int sr = __shfl(s_l, r);
        int dr = __shfl(d_l, r);
        float4 vs = *(const float4*)&fb[(size_t)sr * 64 + c4 * 4];
        float4 vd = *(const float4*)&fb[(size_t)dr * 64 + c4 * 4];
        *(uint2*)&Xw[rloc*136 + c4*4]      = make_uint2(pk2u(vs.x, vs.y), pk2u(vs.z, vs.w));
        *(uint2*)&Xw[rloc*136 + 64 + c4*4] = make_uint2(pk2u(vd.x, vd.y), pk2u(vd.z, vd.w));
    }

    // ================= layer 1: MFMA k<128 + fp32 invariant tail =============
    float4v acc[4];
    #pragma unroll
    for (int nt = 0; nt < 4; ++nt) {
        float bv = b1[nt*16 + l16];
        acc[nt] = (float4v){bv, bv, bv, bv};
    }
    #pragma unroll
    for (int kk = 0; kk < 4; ++kk) {
        short8 a = *(const short8*)&Xw[l16*136 + kk*32 + q*8];
        #pragma unroll
        for (int nt = 0; nt < 4; ++nt) {
            short8 bf = *(const short8*)&wbuf[W1S_OFF + (((kk*4 + nt)*64) + lane) * 8];
            acc[nt] = __builtin_amdgcn_mfma_f32_16x16x32_bf16(a, bf, acc[nt], 0, 0, 0);
        }
    }
    // invariant tail: row r's iv lives in lane r (r<16)
    float4 iv[4];
    #pragma unroll
    for (int i = 0; i < 4; ++i) {
        int r = q*4 + i;
        iv[i] = make_float4(__shfl(ivx, r), __shfl(ivy, r),
                            __shfl(ivz, r), __shfl(ivw, r));
    }
    #pragma unroll
    for (int nt = 0; nt < 4; ++nt) {
        float wa = W1[128*64 + nt*16 + l16];
        float wb = W1[129*64 + nt*16 + l16];
        float wc = W1[130*64 + nt*16 + l16];
        float wd = W1[131*64 + nt*16 + l16];
        #pragma unroll
        for (int i = 0; i < 4; ++i)
            acc[nt][i] += iv[i].x*wa + iv[i].y*wb + iv[i].z*wc + iv[i].w*wd;
    }
    #pragma unroll
    for (int nt = 0; nt < 4; ++nt)
        #pragma unroll
        for (int i = 0; i < 4; ++i)
            Hw[(q*4 + i)*72 + nt*16 + l16] = f2b(silu_(acc[nt][i]));

    // ================= layer 2 -> messages ===================================
    float4v mac[4];
    #pragma unroll
    for (int nt = 0; nt < 4; ++nt) {
        float bv = b2[nt*16 + l16];
        mac[nt] = (float4v){bv, bv, bv, bv};
    }
    #pragma unroll
    for (int kk = 0; kk < 2; ++kk) {
        short8 a = *(const short8*)&Hw[l16*72 + kk*32 + q*8];
        #pragma unroll
        for (int nt = 0; nt < 4; ++nt) {
            short8 bf = *(const short8*)&wbuf[W2S_OFF + (((kk*4 + nt)*64) + lane) * 8];
            mac[nt] = __builtin_amdgcn_mfma_f32_16x16x32_bf16(a, bf, mac[nt], 0, 0, 0);
        }
    }
    #pragma unroll
    for (int nt = 0; nt < 4; ++nt)
        #pragma unroll
        for (int i = 0; i < 4; ++i)
            Mw[(q*4 + i)*72 + nt*16 + l16] = f2b(mac[nt][i]);

    // ================= gate: wt = tanh(silu(M @ P1 + pb1) @ P2 + pb2) ========
    float4v gac[4];
    #pragma unroll
    for (int nt = 0; nt < 4; ++nt) {
        float bv = pb1[nt*16 + l16];
        gac[nt] = (float4v){bv, bv, bv, bv};
    }
    #pragma unroll
    for (int kk = 0; kk < 2; ++kk) {
        short8 a = *(const short8*)&Mw[l16*72 + kk*32 + q*8];
        #pragma unroll
        for (int nt = 0; nt < 4; ++nt) {
            short8 bf = *(const short8*)&wbuf[P1S_OFF + (((kk*4 + nt)*64) + lane) * 8];
            gac[nt] = __builtin_amdgcn_mfma_f32_16x16x32_bf16(a, bf, gac[nt], 0, 0, 0);
        }
    }
    float p2v[4];
    #pragma unroll
    for (int nt = 0; nt < 4; ++nt) p2v[nt] = P2[nt*16 + l16];
    const float pb2v = pb2[0];

    float* wb_ = wts + (size_t)b * E_ + i0;
    #pragma unroll
    for (int i = 0; i < 4; ++i) {
        float p = 0.f;
        #pragma unroll
        for (int nt = 0; nt < 4; ++nt) p += silu_(gac[nt][i]) * p2v[nt];
        p += __shfl_xor(p, 8);
        p += __shfl_xor(p, 4);
        p += __shfl_xor(p, 2);
        p += __shfl_xor(p, 1);
        float wt = tanhf(p + pb2v);
        if (l16 == 0) wb_[w*16 + q*4 + i] = wt;
    }

    // ================= messages -> contiguous bf16 rows ======================
    unsigned short* Mg = Msort + ((size_t)b * E_ + i0 + w*16) * 64;
    #pragma unroll
    for (int it = 0; it < 4; ++it) {
        int row = it * 4 + rr4;
        uint2 v = *(const uint2*)&Mw[row*72 + c4*4];
        *(uint2*)&Mg[row*64 + c4*4] = v;
    }
}

// ---------------------------------------------------------------------------
// Segment-sum of message rows per dst node (segment = off[c] .. off[c]+cnt[c]);
// apply 1/max(deg,1); write bf16 agg rows. One wave per (b,node).
// ---------------------------------------------------------------------------
__global__ __launch_bounds__(256) void agg_kernel(
    const unsigned short* __restrict__ Msort, const int* __restrict__ off,
    const int* __restrict__ cnt, const float* __restrict__ deg,
    unsigned short* __restrict__ aggb)
{
    int wid = (blockIdx.x * 256 + threadIdx.x) >> 6;
    int lane = threadIdx.x & 63;
    if (wid >= B_ * C_) return;
    int b = wid / C_, c = wid - b * C_;
    int j0 = off[c], n = cnt[c];
    const unsigned short* Mb = Msort + ((size_t)b * E_ + j0) * 64;
    float a0 = 0.f, a1 = 0.f;
    int j = 0;
    for (; j + 2 <= n; j += 2) {
        a0 += b2f(Mb[(size_t)j * 64 + lane]);
        a1 += b2f(Mb[(size_t)(j+1) * 64 + lane]);
    }
    if (j < n) a0 += b2f(Mb[(size_t)j * 64 + lane]);
    float sc = 1.f / fmaxf(deg[c], 1.f);
    aggb[(size_t)wid * 64 + lane] = f2b((a0 + a1) * sc);
}

// ---------------------------------------------------------------------------
// Position update: one wave per (b,node). out_pos = pos + sum wt_j*(pos_sj-pos_d)
// ---------------------------------------------------------------------------
__global__ __launch_bounds__(256) void pos_kernel(
    const float* __restrict__ pos, const int* __restrict__ ssrc,
    const int* __restrict__ off, const int* __restrict__ cnt,
    const float* __restrict__ wts, float* __restrict__ out_pos)
{
    int wid = (blockIdx.x * 256 + threadIdx.x) >> 6;
    int lane = threadIdx.x & 63;
    if (wid >= B_ * C_) return;
    int b = wid / C_, c = wid - b * C_;
    int j0 = off[c], n = cnt[c];
    const float* pb = pos + (size_t)b * C_ * P_;
    float px = pb[c*3+0], py = pb[c*3+1], pz = pb[c*3+2];
    float ax = 0.f, ay = 0.f, az = 0.f;
    const float* wb_ = wts + (size_t)b * E_;
    for (int j = lane; j < n; j += 64) {
        float wt = wb_[j0 + j];
        int s = ssrc[j0 + j];
        ax += wt * (pb[s*3+0] - px);
        ay += wt * (pb[s*3+1] - py);
        az += wt * (pb[s*3+2] - pz);
    }
    #pragma unroll
    for (int s = 32; s >= 1; s >>= 1) {
        ax += __shfl_xor(ax, s);
        ay += __shfl_xor(ay, s);
        az += __shfl_xor(az, s);
    }
    if (lane < 3) {
        float base = (lane == 0) ? px : (lane == 1) ? py : pz;
        float add  = (lane == 0) ? ax : (lane == 1) ? ay : az;
        out_pos[(size_t)wid * 3 + lane] = base + add;
    }
}

// ---------------------------------------------------------------------------
// Node update via MFMA, barrier-free wave-private strips.
// ---------------------------------------------------------------------------
__global__ __launch_bounds__(256) void node_kernel(
    const float* __restrict__ feat, const unsigned short* __restrict__ aggb,
    const unsigned short* __restrict__ wbuf,
    const float* __restrict__ ub1, const float* __restrict__ ub2,
    float* __restrict__ out_feat)
{
    __shared__ unsigned short lds[4 * 3328];

    const int tid  = threadIdx.x;
    const int w    = tid >> 6;
    const int lane = tid & 63;
    const int q    = lane >> 4;
    const int l16  = lane & 15;
    const int g0   = blockIdx.x * 64;

    unsigned short* Xw = lds + w * 3328;
    unsigned short* Hw = Xw + 2176;

    const int rr4 = lane >> 4, c4 = lane & 15;
    #pragma unroll
    for (int it = 0; it < 4; ++it) {
        int rloc = it * 4 + rr4;
        int g = g0 + w*16 + rloc;
        float4 vf = *(const float4*)&feat[(size_t)g * 64 + c4 * 4];
        uint2  va = *(const uint2*)&aggb[(size_t)g * 64 + c4 * 4];
        *(uint2*)&Xw[rloc*136 + c4*4]      = make_uint2(pk2u(vf.x, vf.y), pk2u(vf.z, vf.w));
        *(uint2*)&Xw[rloc*136 + 64 + c4*4] = va;
    }

    float4v acc[4];
    #pragma unroll
    for (int nt = 0; nt < 4; ++nt) {
        float bv = ub1[nt*16 + l16];
        acc[nt] = (float4v){bv, bv, bv, bv};
    }
    #pragma unroll
    for (int kk = 0; kk < 4; ++kk) {
        short8 a = *(const short8*)&Xw[l16*136 + kk*32 + q*8];
        #pragma unroll
        for (int nt = 0; nt < 4; ++nt) {
            short8 bf = *(const short8*)&wbuf[U1S_OFF + (((kk*4 + nt)*64) + lane) * 8];
            acc[nt] = __builtin_amdgcn_mfma_f32_16x16x32_bf16(a, bf, acc[nt], 0, 0, 0);
        }
    }
    #pragma unroll
    for (int nt = 0; nt < 4; ++nt)
        #pragma unroll
        for (int i = 0; i < 4; ++i)
            Hw[(q*4 + i)*72 + nt*16 + l16] = f2b(silu_(acc[nt][i]));

    float4v oac[4];
    #pragma unroll
    for (int nt = 0; nt < 4; ++nt) {
        float bv = ub2[nt*16 + l16];
        oac[nt] = (float4v){bv, bv, bv, bv};
    }
    #pragma unroll
    for (int kk = 0; kk < 2; ++kk) {
        short8 a = *(const short8*)&Hw[l16*72 + kk*32 + q*8];
        #pragma unroll
        for (int nt = 0; nt < 4; ++nt) {
            short8 bf = *(const short8*)&wbuf[U2S_OFF + (((kk*4 + nt)*64) + lane) * 8];
            oac[nt] = __builtin_amdgcn_mfma_f32_16x16x32_bf16(a, bf, oac[nt], 0, 0, 0);
        }
    }
    #pragma unroll
    for (int nt = 0; nt < 4; ++nt)
        #pragma unroll
        for (int i = 0; i < 4; ++i) {
            size_t idx = (size_t)(g0 + w*16 + q*4 + i) * 64 + nt*16 + l16;
            out_feat[idx] = feat[idx] + oac[nt][i];
        }
}

extern "C" void kernel_launch(void* const* d_in, const int* in_sizes, int n_in,
                              void* d_out, int out_size, void* d_ws, size_t ws_size,
                              hipStream_t stream) {
    const float* feat = (const float*)d_in[0];
    const float* pos  = (const float*)d_in[1];
    const int*   ei   = (const int*)d_in[2];
    const float* deg  = (const float*)d_in[3];
    const int*   cni  = (const int*)d_in[4];
    const float* mask = (const float*)d_in[5];
    const float* W1   = (const float*)d_in[6];
    const float* b1   = (const float*)d_in[7];
    const float* W2   = (const float*)d_in[8];
    const float* b2   = (const float*)d_in[9];
    const float* P1   = (const float*)d_in[10];
    const float* pb1  = (const float*)d_in[11];
    const float* P2   = (const float*)d_in[12];
    const float* pb2  = (const float*)d_in[13];
    const float* U1   = (const float*)d_in[14];
    const float* ub1  = (const float*)d_in[15];
    const float* U2   = (const float*)d_in[16];
    const float* ub2  = (const float*)d_in[17];

    float* out_feat = (float*)d_out;                       // B*C*H
    float* out_pos  = out_feat + (size_t)B_ * C_ * H_;     // B*C*P

    // workspace layout (~66 MB)
    float* desc = (float*)d_ws;                                  // B*C*40 fp32
    float* wts  = desc + (size_t)B_ * C_ * 40;                   // B*E fp32
    unsigned short* wbuf  = (unsigned short*)(wts + (size_t)B_ * E_);
    unsigned short* Msort = wbuf + WBUF_ELEMS;                   // B*E*64 bf16
    unsigned short* aggb  = Msort + (size_t)B_ * E_ * 64;        // B*C*64 bf16
    int* cnt    = (int*)(aggb + (size_t)B_ * C_ * 64);           // C
    int* total  = cnt + C_;                                      // 1
    int* off    = total + 1;                                     // C
    int* cursor = off + C_;                                      // C
    int* ssrc   = cursor + C_;                                   // E
    int* sdst   = ssrc + E_;                                     // E

    hipMemsetAsync(cnt, 0, (C_ + 1) * sizeof(int), stream);      // cnt + total

    prep_kernel<<<(WBUF_ELEMS + 255) / 256, 256, 0, stream>>>(W1, W2, P1, U1, U2, wbuf);
    hist_kernel<<<(E_ + 255) / 256, 256, 0, stream>>>(ei, cnt);
    desc_kernel<<<(B_ * C_ + 255) / 256, 256, 0, stream>>>(pos, cni, mask, desc);
    alloc_kernel<<<(C_ + 255) / 256, 256, 0, stream>>>(cnt, off, cursor, total);
    scatter_kernel<<<(E_ + 255) / 256, 256, 0, stream>>>(ei, cursor, ssrc, sdst);

    edge_kernel<<<B_ * ET_, 256, 0, stream>>>(
        feat, ssrc, sdst, desc, wbuf, W1, b1, b2, pb1, P2, pb2, Msort, wts);

    agg_kernel<<<(B_ * C_) / 4, 256, 0, stream>>>(Msort, off, cnt, deg, aggb);
    pos_kernel<<<(B_ * C_) / 4, 256, 0, stream>>>(pos, ssrc, off, cnt, wts, out_pos);

    node_kernel<<<(B_ * C_) / 64, 256, 0, stream>>>(
        feat, aggb, wbuf, ub1, ub2, out_feat);
}

// Round 6
// 226.527 us; speedup vs baseline: 1.2265x; 1.0908x over previous
//
#include <hip/hip_runtime.h>
#include <hip/hip_bf16.h>

#define B_ 2
#define C_ 20000
#define H_ 64
#define M_ 8
#define E_ 200000
#define P_ 3
#define EPS_ 1e-12f
#define ET_ (E_ / 64)   // edge tiles per batch = 3125

typedef __attribute__((ext_vector_type(8))) short short8;
typedef __attribute__((ext_vector_type(4))) float float4v;

__device__ __forceinline__ float silu_(float x) {
    return x / (1.f + __expf(-x));
}
__device__ __forceinline__ unsigned short f2b(float f) {
    unsigned u = __float_as_uint(f);
    unsigned r = (u + 0x7FFF + ((u >> 16) & 1)) >> 16;   // RNE fp32->bf16
    return (unsigned short)r;
}
__device__ __forceinline__ float b2f(unsigned short h) {
    return __uint_as_float(((unsigned)h) << 16);
}
__device__ __forceinline__ unsigned pk2u(float a, float b) {
    __hip_bfloat162 h = __float22bfloat162_rn(make_float2(a, b)); // v_cvt_pk_bf16_f32
    unsigned u; __builtin_memcpy(&u, &h, sizeof(u)); return u;
}

// bf16 B-fragment-swizzled weights (K multiples of 32; W1 rows 128..131 on VALU)
#define W1S_OFF 0
#define W2S_OFF 8192
#define P1S_OFF 12288
#define U1S_OFF 16384
#define U2S_OFF 24576
#define WBUF_ELEMS 28672

// combo_kernel block ranges (all parts independent)
#define NB_PREP  120                     // 28672 weight-frag elems
#define NB_FEATB 2500                    // B*C*64/4 = 640000 threads
#define NB_DESC  157                     // ceil(B*C/256)
#define NB_HIST  782                     // ceil(E/256)
#define NB_COMBO (NB_PREP + NB_FEATB + NB_DESC + NB_HIST)

__global__ __launch_bounds__(256) void combo_kernel(
    const float* __restrict__ W1, const float* __restrict__ W2,
    const float* __restrict__ P1, const float* __restrict__ U1,
    const float* __restrict__ U2, unsigned short* __restrict__ wbuf,
    const float* __restrict__ feat, unsigned short* __restrict__ featb,
    const float* __restrict__ pos, const int* __restrict__ cni,
    const float* __restrict__ mask, float* __restrict__ desc,
    const int* __restrict__ ei, int* __restrict__ cnt)
{
    const int bid = blockIdx.x;
    if (bid < NB_PREP) {
        // ---- weight swizzle -> bf16 B-fragments
        int t = bid * 256 + threadIdx.x;
        if (t >= WBUF_ELEMS) return;
        const float* W; int e;
        if (t < W2S_OFF)      { W = W1; e = t; }
        else if (t < U1S_OFF) { W = (t < P1S_OFF) ? W2 : P1; e = (t < P1S_OFF) ? t - W2S_OFF : t - P1S_OFF; }
        else if (t < U2S_OFF) { W = U1; e = t - U1S_OFF; }
        else                  { W = U2; e = t - U2S_OFF; }
        int j = e & 7, lane = (e >> 3) & 63, nt = (e >> 9) & 3, kk = e >> 11;
        int k = kk * 32 + ((lane >> 4) * 8) + j;
        int n = nt * 16 + (lane & 15);
        wbuf[t] = f2b(W[k * 64 + n]);
    } else if (bid < NB_PREP + NB_FEATB) {
        // ---- features -> bf16 cache (coalesced)
        int t = (bid - NB_PREP) * 256 + threadIdx.x;   // < 640000 exactly
        float4 v = *(const float4*)&feat[(size_t)t * 4];
        *(uint2*)&featb[(size_t)t * 4] = make_uint2(pk2u(v.x, v.y), pk2u(v.z, v.w));
    } else if (bid < NB_PREP + NB_FEATB + NB_DESC) {
        // ---- per-(b,cell) descriptor: 8x(x,y,z,m) + centroid + own pos
        int tid = (bid - NB_PREP - NB_FEATB) * 256 + threadIdx.x;
        if (tid >= B_ * C_) return;
        int b = tid / C_, c = tid - b * C_;
        const float* pb = pos + (size_t)b * C_ * P_;
        float4* D = (float4*)(desc + (size_t)tid * 40);
        int4 n0 = *(const int4*)&cni[c*8];
        int4 n1 = *(const int4*)&cni[c*8 + 4];
        float4 m0 = *(const float4*)&mask[c*8];
        float4 m1 = *(const float4*)&mask[c*8 + 4];
        int ni[8] = {n0.x, n0.y, n0.z, n0.w, n1.x, n1.y, n1.z, n1.w};
        float mm[8] = {m0.x, m0.y, m0.z, m0.w, m1.x, m1.y, m1.z, m1.w};
        float sx = 0.f, sy = 0.f, sz = 0.f, sm = 0.f;
        #pragma unroll
        for (int m = 0; m < 8; ++m) {
            float x = pb[ni[m]*3+0], y = pb[ni[m]*3+1], z = pb[ni[m]*3+2];
            D[m] = make_float4(x, y, z, mm[m]);
            sx += x * mm[m]; sy += y * mm[m]; sz += z * mm[m]; sm += mm[m];
        }
        float inv = 1.f / fmaxf(sm, EPS_);
        D[8] = make_float4(sx * inv, sy * inv, sz * inv, sm);
        D[9] = make_float4(pb[c*3+0], pb[c*3+1], pb[c*3+2], 0.f);
    } else {
        // ---- dst histogram
        int e = (bid - NB_PREP - NB_FEATB - NB_DESC) * 256 + threadIdx.x;
        if (e >= E_) return;
        atomicAdd(&cnt[ei[E_ + e]], 1);
    }
}

// ---------------------------------------------------------------------------
// alloc: wave-scan + one atomic bump per wave -> cursor (segment order free)
// ---------------------------------------------------------------------------
__global__ __launch_bounds__(256) void alloc_kernel(
    const int* __restrict__ cnt, int* __restrict__ cursor, int* __restrict__ total)
{
    int idx = blockIdx.x * 256 + threadIdx.x;
    int lane = threadIdx.x & 63;
    int v = (idx < C_) ? cnt[idx] : 0;
    int inc = v;
    #pragma unroll
    for (int s = 1; s < 64; s <<= 1) {
        int n = __shfl_up(inc, s);
        if (lane >= s) inc += n;
    }
    int wtot = __shfl(inc, 63);
    int base = 0;
    if (lane == 0) base = atomicAdd(total, wtot);
    base = __shfl(base, 0);
    if (idx < C_) cursor[idx] = base + inc - v;
}

__global__ __launch_bounds__(256) void scatter_kernel(
    const int* __restrict__ ei, int* __restrict__ cursor,
    int* __restrict__ ssrc, int* __restrict__ sdst)
{
    int e = blockIdx.x * 256 + threadIdx.x;
    if (e >= E_) return;
    int s = ei[e], d = ei[E_ + e];
    int slot = atomicAdd(&cursor[d], 1);
    ssrc[slot] = s;
    sdst[slot] = d;
}

// ---------------------------------------------------------------------------
// Edge kernel: fused geometry + 3 MFMA MLP stages + in-wave segmented
// aggregation (dst-sorted -> ~2.6 segments per 16-edge wave).
// 4 independent waves/block, barrier-free wave-private LDS arenas.
// ---------------------------------------------------------------------------
__global__ __launch_bounds__(256) void edge_kernel(
    const unsigned short* __restrict__ featb,
    const int* __restrict__ ssrc, const int* __restrict__ sdst,
    const float* __restrict__ desc,
    const unsigned short* __restrict__ wbuf, const float* __restrict__ W1,
    const float* __restrict__ b1, const float* __restrict__ b2,
    const float* __restrict__ pb1, const float* __restrict__ P2,
    const float* __restrict__ pb2,
    float* __restrict__ aggf, float* __restrict__ out_pos)
{
    __shared__ unsigned short lds[4 * 3328];   // 26624 B -> 6 blocks/CU

    const int tid  = threadIdx.x;
    const int w    = tid >> 6;
    const int lane = tid & 63;
    const int q    = lane >> 4;
    const int l16  = lane & 15;
    const int w16  = w * 16;

    const int tile = blockIdx.x;
    const int b    = tile / ET_;
    const int i0   = (tile - b * ET_) * 64;
    const int s_l  = ssrc[i0 + lane];
    const int d_l  = sdst[i0 + lane];
    const unsigned short* fb = featb + (size_t)b * C_ * H_;

    unsigned short* Xw = lds + w * 3328;
    unsigned short* Hw = Xw + 2176;
    unsigned short* Mw = Xw;   // alias: X dead before M written (dep chain)

    // ================= geometry (edge = w16 + l16, j-split across quads) =====
    const int sg = __shfl(s_l, w16 + l16);
    const int dg = __shfl(d_l, w16 + l16);
    const float4* Ds = (const float4*)(desc + ((size_t)b * C_ + sg) * 40);
    const float4* Dd = (const float4*)(desc + ((size_t)b * C_ + dg) * 40);

    float4 S[8];
    float sp2[8], rowmin[8];
    const float INFV = __builtin_inff();
    #pragma unroll
    for (int i = 0; i < 8; ++i) {
        S[i] = Ds[i];
        sp2[i] = S[i].x*S[i].x + S[i].y*S[i].y + S[i].z*S[i].z;
        rowmin[i] = INFV;
    }
    float pair = 0.f, hyx = 0.f;
    #pragma unroll
    for (int jj = 0; jj < 2; ++jj) {
        float4 Dj = Dd[q*2 + jj];
        float dp2 = Dj.x*Dj.x + Dj.y*Dj.y + Dj.z*Dj.z;
        float colmin = INFV;
        #pragma unroll
        for (int i = 0; i < 8; ++i) {
            float cr = S[i].x*Dj.x + S[i].y*Dj.y + S[i].z*Dj.z;
            float dd = sqrtf(fmaxf(sp2[i] + dp2 - 2.f*cr, 0.f) + EPS_);
            pair += dd * S[i].w * Dj.w;
            rowmin[i] = (Dj.w  > 0.f) ? fminf(rowmin[i], dd) : rowmin[i];
            colmin    = (S[i].w > 0.f) ? fminf(colmin, dd)    : colmin;
        }
        hyx = fmaxf(hyx, (Dj.w > 0.f) ? colmin : 0.f);
    }
    pair += __shfl_xor(pair, 16);  pair += __shfl_xor(pair, 32);
    hyx = fmaxf(hyx, __shfl_xor(hyx, 16));  hyx = fmaxf(hyx, __shfl_xor(hyx, 32));
    #pragma unroll
    for (int i = 0; i < 8; ++i) {
        rowmin[i] = fminf(rowmin[i], __shfl_xor(rowmin[i], 16));
        rowmin[i] = fminf(rowmin[i], __shfl_xor(rowmin[i], 32));
    }
    float hxy = 0.f;
    #pragma unroll
    for (int i = 0; i < 8; ++i)
        hxy = fmaxf(hxy, (S[i].w > 0.f) ? rowmin[i] : 0.f);
    float4 Sc = Ds[8], Dc = Dd[8];
    float cdx = Sc.x - Dc.x, cdy = Sc.y - Dc.y, cdz = Sc.z - Dc.z;
    float4 Sp = Ds[9], Dp = Dd[9];
    const float relx = Sp.x - Dp.x, rely = Sp.y - Dp.y, relz = Sp.z - Dp.z;
    const float ivx = sqrtf(relx*relx + rely*rely + relz*relz);  // dist
    const float ivy = pair;                                      // pairwise
    const float ivz = sqrtf(cdx*cdx + cdy*cdy + cdz*cdz);        // centroid
    const float ivw = fmaxf(hxy, hyx);                           // hausdorff

    // ================= stage X = [h_src | h_dst] from bf16 cache =============
    const int rr4 = lane >> 4, c4 = lane & 15;
    #pragma unroll
    for (int it = 0; it < 4; ++it) {
        int rloc = it * 4 + rr4;
        int r = w16 + rloc;
        int sr = __shfl(s_l, r);
        int dr = __shfl(d_l, r);
        uint2 vs = *(const uint2*)&fb[(size_t)sr * 64 + c4 * 4];
        uint2 vd = *(const uint2*)&fb[(size_t)dr * 64 + c4 * 4];
        *(uint2*)&Xw[rloc*136 + c4*4]      = vs;
        *(uint2*)&Xw[rloc*136 + 64 + c4*4] = vd;
    }

    // ================= layer 1: MFMA k<128 + fp32 invariant tail =============
    float4v acc[4];
    #pragma unroll
    for (int nt = 0; nt < 4; ++nt) {
        float bv = b1[nt*16 + l16];
        acc[nt] = (float4v){bv, bv, bv, bv};
    }
    #pragma unroll
    for (int kk = 0; kk < 4; ++kk) {
        short8 a = *(const short8*)&Xw[l16*136 + kk*32 + q*8];
        #pragma unroll
        for (int nt = 0; nt < 4; ++nt) {
            short8 bf = *(const short8*)&wbuf[W1S_OFF + (((kk*4 + nt)*64) + lane) * 8];
            acc[nt] = __builtin_amdgcn_mfma_f32_16x16x32_bf16(a, bf, acc[nt], 0, 0, 0);
        }
    }
    float4 iv[4];
    #pragma unroll
    for (int i = 0; i < 4; ++i) {
        int r = q*4 + i;
        iv[i] = make_float4(__shfl(ivx, r), __shfl(ivy, r),
                            __shfl(ivz, r), __shfl(ivw, r));
    }
    #pragma unroll
    for (int nt = 0; nt < 4; ++nt) {
        float wa = W1[128*64 + nt*16 + l16];
        float wb = W1[129*64 + nt*16 + l16];
        float wc = W1[130*64 + nt*16 + l16];
        float wd = W1[131*64 + nt*16 + l16];
        #pragma unroll
        for (int i = 0; i < 4; ++i)
            acc[nt][i] += iv[i].x*wa + iv[i].y*wb + iv[i].z*wc + iv[i].w*wd;
    }
    #pragma unroll
    for (int nt = 0; nt < 4; ++nt)
        #pragma unroll
        for (int i = 0; i < 4; ++i)
            Hw[(q*4 + i)*72 + nt*16 + l16] = f2b(silu_(acc[nt][i]));

    // ================= layer 2 -> messages ===================================
    float4v mac[4];
    #pragma unroll
    for (int nt = 0; nt < 4; ++nt) {
        float bv = b2[nt*16 + l16];
        mac[nt] = (float4v){bv, bv, bv, bv};
    }
    #pragma unroll
    for (int kk = 0; kk < 2; ++kk) {
        short8 a = *(const short8*)&Hw[l16*72 + kk*32 + q*8];
        #pragma unroll
        for (int nt = 0; nt < 4; ++nt) {
            short8 bf = *(const short8*)&wbuf[W2S_OFF + (((kk*4 + nt)*64) + lane) * 8];
            mac[nt] = __builtin_amdgcn_mfma_f32_16x16x32_bf16(a, bf, mac[nt], 0, 0, 0);
        }
    }
    #pragma unroll
    for (int nt = 0; nt < 4; ++nt)
        #pragma unroll
        for (int i = 0; i < 4; ++i)
            Mw[(q*4 + i)*72 + nt*16 + l16] = f2b(mac[nt][i]);

    // ================= gate: wt = tanh(silu(M @ P1 + pb1) @ P2 + pb2) ========
    float4v gac[4];
    #pragma unroll
    for (int nt = 0; nt < 4; ++nt) {
        float bv = pb1[nt*16 + l16];
        gac[nt] = (float4v){bv, bv, bv, bv};
    }
    #pragma unroll
    for (int kk = 0; kk < 2; ++kk) {
        short8 a = *(const short8*)&Mw[l16*72 + kk*32 + q*8];
        #pragma unroll
        for (int nt = 0; nt < 4; ++nt) {
            short8 bf = *(const short8*)&wbuf[P1S_OFF + (((kk*4 + nt)*64) + lane) * 8];
            gac[nt] = __builtin_amdgcn_mfma_f32_16x16x32_bf16(a, bf, gac[nt], 0, 0, 0);
        }
    }
    float p2v[4];
    #pragma unroll
    for (int nt = 0; nt < 4; ++nt) p2v[nt] = P2[nt*16 + l16];
    const float pb2v = pb2[0];

    #pragma unroll
    for (int i = 0; i < 4; ++i) {
        float p = 0.f;
        #pragma unroll
        for (int nt = 0; nt < 4; ++nt) p += silu_(gac[nt][i]) * p2v[nt];
        p += __shfl_xor(p, 8);
        p += __shfl_xor(p, 4);
        p += __shfl_xor(p, 2);
        p += __shfl_xor(p, 1);
        float wt = tanhf(p + pb2v);
        // store wt in spare columns 64..65 of the message row (fp32-aligned)
        if (l16 == 0) *(float*)&Mw[(q*4 + i)*72 + 64] = wt;
    }

    // ================= in-wave segmented aggregation =========================
    // Pre-load all 16 message rows (independent LDS reads) + per-row gate.
    float mrow[16];
    #pragma unroll
    for (int rr = 0; rr < 16; ++rr) mrow[rr] = b2f(Mw[rr*72 + lane]);
    float wtl = *(const float*)&Mw[l16*72 + 64];   // lane l16 holds row l16's wt

    float* aggB = aggf + (size_t)b * C_ * 64;
    float* opB  = out_pos + (size_t)b * C_ * 3;

    int dprev = __shfl(d_l, w16);
    float colacc = 0.f, pxa = 0.f, pya = 0.f, pza = 0.f;
    #pragma unroll
    for (int rr = 0; rr < 16; ++rr) {
        int dcur = __shfl(d_l, w16 + rr);          // wave-uniform
        if (dcur != dprev) {                       // uniform branch
            atomicAdd(&aggB[(size_t)dprev * 64 + lane], colacc);
            if (lane < 3) {
                float v = (lane == 0) ? pxa : (lane == 1) ? pya : pza;
                atomicAdd(&opB[(size_t)dprev * 3 + lane], v);
            }
            colacc = 0.f; pxa = 0.f; pya = 0.f; pza = 0.f;
            dprev = dcur;
        }
        float wt = __shfl(wtl, rr);
        colacc += mrow[rr];
        pxa += wt * __shfl(relx, rr);
        pya += wt * __shfl(rely, rr);
        pza += wt * __shfl(relz, rr);
    }
    atomicAdd(&aggB[(size_t)dprev * 64 + lane], colacc);
    if (lane < 3) {
        float v = (lane == 0) ? pxa : (lane == 1) ? pya : pza;
        atomicAdd(&opB[(size_t)dprev * 3 + lane], v);
    }
}

// ---------------------------------------------------------------------------
// Node update via MFMA, barrier-free wave-private strips.
// X = [featb | agg/max(deg,1)]; out = feat + MLP(X)
// ---------------------------------------------------------------------------
__global__ __launch_bounds__(256) void node_kernel(
    const float* __restrict__ feat, const unsigned short* __restrict__ featb,
    const float* __restrict__ aggf, const float* __restrict__ deg,
    const unsigned short* __restrict__ wbuf,
    const float* __restrict__ ub1, const float* __restrict__ ub2,
    float* __restrict__ out_feat)
{
    __shared__ unsigned short lds[4 * 3328];

    const int tid  = threadIdx.x;
    const int w    = tid >> 6;
    const int lane = tid & 63;
    const int q    = lane >> 4;
    const int l16  = lane & 15;
    const int g0   = blockIdx.x * 64;

    unsigned short* Xw = lds + w * 3328;
    unsigned short* Hw = Xw + 2176;

    const int rr4 = lane >> 4, c4 = lane & 15;
    #pragma unroll
    for (int it = 0; it < 4; ++it) {
        int rloc = it * 4 + rr4;
        int g = g0 + w*16 + rloc;
        int gc = (g >= C_) ? g - C_ : g;
        float sc = 1.f / fmaxf(deg[gc], 1.f);
        uint2  vf = *(const uint2*)&featb[(size_t)g * 64 + c4 * 4];
        float4 va = *(const float4*)&aggf[(size_t)g * 64 + c4 * 4];
        *(uint2*)&Xw[rloc*136 + c4*4]      = vf;
        *(uint2*)&Xw[rloc*136 + 64 + c4*4] =
            make_uint2(pk2u(va.x*sc, va.y*sc), pk2u(va.z*sc, va.w*sc));
    }

    float4v acc[4];
    #pragma unroll
    for (int nt = 0; nt < 4; ++nt) {
        float bv = ub1[nt*16 + l16];
        acc[nt] = (float4v){bv, bv, bv, bv};
    }
    #pragma unroll
    for (int kk = 0; kk < 4; ++kk) {
        short8 a = *(const short8*)&Xw[l16*136 + kk*32 + q*8];
        #pragma unroll
        for (int nt = 0; nt < 4; ++nt) {
            short8 bf = *(const short8*)&wbuf[U1S_OFF + (((kk*4 + nt)*64) + lane) * 8];
            acc[nt] = __builtin_amdgcn_mfma_f32_16x16x32_bf16(a, bf, acc[nt], 0, 0, 0);
        }
    }
    #pragma unroll
    for (int nt = 0; nt < 4; ++nt)
        #pragma unroll
        for (int i = 0; i < 4; ++i)
            Hw[(q*4 + i)*72 + nt*16 + l16] = f2b(silu_(acc[nt][i]));

    float4v oac[4];
    #pragma unroll
    for (int nt = 0; nt < 4; ++nt) {
        float bv = ub2[nt*16 + l16];
        oac[nt] = (float4v){bv, bv, bv, bv};
    }
    #pragma unroll
    for (int kk = 0; kk < 2; ++kk) {
        short8 a = *(const short8*)&Hw[l16*72 + kk*32 + q*8];
        #pragma unroll
        for (int nt = 0; nt < 4; ++nt) {
            short8 bf = *(const short8*)&wbuf[U2S_OFF + (((kk*4 + nt)*64) + lane) * 8];
            oac[nt] = __builtin_amdgcn_mfma_f32_16x16x32_bf16(a, bf, oac[nt], 0, 0, 0);
        }
    }
    #pragma unroll
    for (int nt = 0; nt < 4; ++nt)
        #pragma unroll
        for (int i = 0; i < 4; ++i) {
            size_t idx = (size_t)(g0 + w*16 + q*4 + i) * 64 + nt*16 + l16;
            out_feat[idx] = feat[idx] + oac[nt][i];
        }
}

extern "C" void kernel_launch(void* const* d_in, const int* in_sizes, int n_in,
                              void* d_out, int out_size, void* d_ws, size_t ws_size,
                              hipStream_t stream) {
    const float* feat = (const float*)d_in[0];
    const float* pos  = (const float*)d_in[1];
    const int*   ei   = (const int*)d_in[2];
    const float* deg  = (const float*)d_in[3];
    const int*   cni  = (const int*)d_in[4];
    const float* mask = (const float*)d_in[5];
    const float* W1   = (const float*)d_in[6];
    const float* b1   = (const float*)d_in[7];
    const float* W2   = (const float*)d_in[8];
    const float* b2   = (const float*)d_in[9];
    const float* P1   = (const float*)d_in[10];
    const float* pb1  = (const float*)d_in[11];
    const float* P2   = (const float*)d_in[12];
    const float* pb2  = (const float*)d_in[13];
    const float* U1   = (const float*)d_in[14];
    const float* ub1  = (const float*)d_in[15];
    const float* U2   = (const float*)d_in[16];
    const float* ub2  = (const float*)d_in[17];

    float* out_feat = (float*)d_out;                       // B*C*H
    float* out_pos  = out_feat + (size_t)B_ * C_ * H_;     // B*C*P

    // workspace layout (~24 MB)
    float* desc = (float*)d_ws;                                  // B*C*40 fp32
    float* aggf = desc + (size_t)B_ * C_ * 40;                   // B*C*64 fp32
    unsigned short* featb = (unsigned short*)(aggf + (size_t)B_ * C_ * 64); // B*C*64
    unsigned short* wbuf  = featb + (size_t)B_ * C_ * 64;        // 28672
    int* cnt    = (int*)(wbuf + WBUF_ELEMS);                     // C
    int* total  = cnt + C_;                                      // 1
    int* cursor = total + 1;                                     // C
    int* ssrc   = cursor + C_;                                   // E
    int* sdst   = ssrc + E_;                                     // E

    hipMemsetAsync(cnt, 0, (C_ + 1) * sizeof(int), stream);      // cnt + total
    hipMemsetAsync(aggf, 0, (size_t)B_ * C_ * 64 * sizeof(float), stream);
    hipMemcpyAsync(out_pos, pos, (size_t)B_ * C_ * P_ * sizeof(float),
                   hipMemcpyDeviceToDevice, stream);

    combo_kernel<<<NB_COMBO, 256, 0, stream>>>(
        W1, W2, P1, U1, U2, wbuf, feat, featb, pos, cni, mask, desc, ei, cnt);

    alloc_kernel<<<(C_ + 255) / 256, 256, 0, stream>>>(cnt, cursor, total);
    scatter_kernel<<<(E_ + 255) / 256, 256, 0, stream>>>(ei, cursor, ssrc, sdst);

    edge_kernel<<<B_ * ET_, 256, 0, stream>>>(
        featb, ssrc, sdst, desc, wbuf, W1, b1, b2, pb1, P2, pb2, aggf, out_pos);

    node_kernel<<<(B_ * C_) / 64, 256, 0, stream>>>(
        feat, featb, aggf, deg, wbuf, ub1, ub2, out_feat);
}